// Round 3
// baseline (301.944 us; speedup 1.0000x reference)
//
#include <hip/hip_runtime.h>
#include <cstddef>
#include <cstdint>

#define IN_DIM 256
#define H_DIM  128
#define C_DIM  40
#define BM     128
#define LDH    136   // ushort stride, phase-2 h / w2 tiles (272 B rows, conflict-free)
#define PAD_C  40    // z row width in bf16 cols: 40 cols = 80 B
#define W2_ROWS 64   // w2t padded n-rows (two 32-col MFMA tiles)

typedef short bf16x8 __attribute__((ext_vector_type(8)));
typedef float f32x16 __attribute__((ext_vector_type(16)));
typedef uint  u32x4  __attribute__((ext_vector_type(4)));

__device__ __forceinline__ ushort f2bf(float f) {   // RNE fp32 -> bf16
  uint u = __builtin_bit_cast(uint, f);
  u += 0x7fffu + ((u >> 16) & 1u);
  return (ushort)(u >> 16);
}
__device__ __forceinline__ float bf2f(uint s) {     // low 16 bits -> f32
  uint u = s << 16;
  return __builtin_bit_cast(float, u);
}
// packed fp32x2 -> bf16x2 (HW cvt if available; manual RNE fallback)
__device__ __forceinline__ uint pack2bf(float a, float b) {
#if __has_builtin(__builtin_amdgcn_cvt_pk_bf16_f32)
  typedef __bf16 bf16v2 __attribute__((ext_vector_type(2)));
  bf16v2 r = __builtin_amdgcn_cvt_pk_bf16_f32(a, b);
  return __builtin_bit_cast(uint, r);
#else
  return (uint)f2bf(a) | ((uint)f2bf(b) << 16);
#endif
}

// ---------------------------------------------------------------------------
// Setup: CSR row_ptr (lower_bound per node) + weight conversion in one launch.
// W1 [256][128] f32 -> w1t [128][256] bf16 ; W2 [128][40] f32 -> w2t [64][128]
// bf16 (n-major, zero-padded n=40..63).
// ---------------------------------------------------------------------------
__global__ void setup_kernel(const int* __restrict__ dst, int E,
                             int* __restrict__ row_ptr, int n1,
                             const float* __restrict__ W1,
                             const float* __restrict__ W2,
                             ushort* __restrict__ w1t,
                             ushort* __restrict__ w2t) {
  int tid = blockIdx.x * blockDim.x + threadIdx.x;
  if (tid < IN_DIM * H_DIM) {
    int k = tid >> 7, n = tid & 127;
    w1t[n * IN_DIM + k] = f2bf(W1[tid]);
  } else if (tid < IN_DIM * H_DIM + W2_ROWS * H_DIM) {
    int i = tid - IN_DIM * H_DIM;                   // 0..8191
    int n = i >> 7, k = i & 127;
    w2t[i] = (n < C_DIM) ? f2bf(W2[k * C_DIM + n]) : (ushort)0;
  }
  if (tid < n1) {
    int lo = 0, hi = E;
    while (lo < hi) {
      int mid = (lo + hi) >> 1;
      if (dst[mid] < tid) lo = mid + 1; else hi = mid;
    }
    row_ptr[tid] = lo;
  }
}

// ---------------------------------------------------------------------------
// Fused dense MLP: z0[n][0:40] = relu(feat[n] @ W1) @ W2, bf16, row stride 40.
// Block 256 thr (4 waves), 128-node tile, 52224 B LDS -> 3 blocks/CU.
// GEMM1 is barrier-free and LDS-free: MFMA A-fragments load straight from
// feat (lane l + lane l+32 consume one full 64-B sector of row l&31; feat
// read exactly once), B-fragments straight from L2-resident w1t (64 KB).
// fp32->bf16 conversion in-register (cvt_pk). Depth-1 ping-pong prefetch,
// compile-time buffer indices (full unroll) so everything stays in VGPRs.
// Phase 2: relu(h) -> LDS rows, w2t -> LDS, GEMM2 via MFMA (unchanged).
// ---------------------------------------------------------------------------
__global__ __launch_bounds__(256, 3) void fused_dense_kernel(
    const float* __restrict__ feat, const ushort* __restrict__ w1t,
    const ushort* __restrict__ w2t, ushort* __restrict__ z0, int N) {
  // phase2 only: h [128][LDH] (34816 B) + w2 [64][LDH] (17408 B) = 52224 B
  __shared__ __align__(16) ushort smem[26112];

  const int t = threadIdx.x;
  const int w = t >> 6, l = t & 63;
  const int nb = blockIdx.x * BM;

  f32x16 acc[4];
#pragma unroll
  for (int tn = 0; tn < 4; ++tn)
#pragma unroll
    for (int r = 0; r < 16; ++r) acc[tn][r] = 0.f;

  // per-lane fragment base pointers
  int rowA = nb + 32 * w + (l & 31);
  if (rowA >= N) rowA = N - 1;
  const float*  ap = feat + (size_t)rowA * IN_DIM + ((l >> 5) << 3);
  const ushort* bp = w1t + ((l & 31) << 8) + ((l >> 5) << 3);

  float4 Ax[2][2];
  bf16x8 Bx[2][4];

#pragma unroll
  for (int ks = 0; ks < 16; ++ks) {     // K = 256, 16 steps of 16
    const int c = ks & 1;
    if (ks == 0) {
      Ax[0][0] = *(const float4*)(ap + 0);
      Ax[0][1] = *(const float4*)(ap + 4);
#pragma unroll
      for (int tn = 0; tn < 4; ++tn)
        Bx[0][tn] = *(const bf16x8*)(bp + tn * (32 * IN_DIM));
    }
    if (ks < 15) {                       // prefetch next K-step
      const int n16 = (ks + 1) * 16;
      Ax[c ^ 1][0] = *(const float4*)(ap + n16);
      Ax[c ^ 1][1] = *(const float4*)(ap + n16 + 4);
#pragma unroll
      for (int tn = 0; tn < 4; ++tn)
        Bx[c ^ 1][tn] = *(const bf16x8*)(bp + tn * (32 * IN_DIM) + n16);
    }
    uint4 pk;
    pk.x = pack2bf(Ax[c][0].x, Ax[c][0].y);
    pk.y = pack2bf(Ax[c][0].z, Ax[c][0].w);
    pk.z = pack2bf(Ax[c][1].x, Ax[c][1].y);
    pk.w = pack2bf(Ax[c][1].z, Ax[c][1].w);
    bf16x8 af = __builtin_bit_cast(bf16x8, pk);
#pragma unroll
    for (int tn = 0; tn < 4; ++tn)
      acc[tn] = __builtin_amdgcn_mfma_f32_32x32x16_bf16(af, Bx[c][tn], acc[tn], 0, 0, 0);
  }

  // ---- phase 2: relu(h) -> LDS rows [node][k], C-layout: col=l&31, node=(r&3)+8*(r>>2)+4*(l>>5)
#pragma unroll
  for (int tn = 0; tn < 4; ++tn) {
    int col = tn * 32 + (l & 31);
#pragma unroll
    for (int r = 0; r < 16; ++r) {
      int nodeLoc = (r & 3) + 8 * (r >> 2) + 4 * (l >> 5) + 32 * w;
      float v = acc[tn][r];
      smem[nodeLoc * LDH + col] = f2bf(v > 0.f ? v : 0.f);
    }
  }
  // stage w2t [64][128] -> LDS [64][LDH]: thread t copies 32 ushorts (4 uint4)
  {
    int row = t >> 2, c4 = (t & 3) << 5;
    const uint4* src = (const uint4*)(w2t + row * H_DIM + c4);
    uint4* dst = (uint4*)(smem + 128 * LDH + row * LDH + c4);
    dst[0] = src[0];
    dst[1] = src[1];
    dst[2] = src[2];
    dst[3] = src[3];
  }
  __syncthreads();

  // GEMM2: wave w -> nodes 32w..+31, n-tiles {0..31, 32..63}, K=128
  f32x16 acc2[2];
#pragma unroll
  for (int tn = 0; tn < 2; ++tn)
#pragma unroll
    for (int r = 0; r < 16; ++r) acc2[tn][r] = 0.f;

  const ushort* Hbase  = smem + (w * 32 + (l & 31)) * LDH + ((l >> 5) << 3);
  const ushort* W2base = smem + 128 * LDH + (l & 31) * LDH + ((l >> 5) << 3);
#pragma unroll
  for (int kb = 0; kb < 8; ++kb) {
    bf16x8 af = *(const bf16x8*)(Hbase + kb * 16);
#pragma unroll
    for (int tn = 0; tn < 2; ++tn) {
      bf16x8 bfr = *(const bf16x8*)(W2base + tn * 32 * LDH + kb * 16);
      acc2[tn] = __builtin_amdgcn_mfma_f32_32x32x16_bf16(af, bfr, acc2[tn], 0, 0, 0);
    }
  }

  // store z0 cols 0..39 only (row stride PAD_C = 40)
#pragma unroll
  for (int tn = 0; tn < 2; ++tn) {
    int col = tn * 32 + (l & 31);
    if (col < C_DIM) {
#pragma unroll
      for (int r = 0; r < 16; ++r) {
        int node = nb + 32 * w + (r & 3) + 8 * (r >> 2) + 4 * (l >> 5);
        if (node < N) z0[(size_t)node * PAD_C + col] = f2bf(acc2[tn][r]);
      }
    }
  }
}

// ---------------------------------------------------------------------------
// SPMM (CSR, dst-sorted): one wave per node. lane = 8*h + j (h = edge slot,
// j = col oct). Rows are 40 bf16 cols = 80 B -> only lanes with j < 5
// gather/FMA. Main loop unrolled x2 (16 edges/iter). Butterfly-reduce slots.
// ---------------------------------------------------------------------------
__global__ __launch_bounds__(256) void spmm_kernel(
    const int* __restrict__ row_ptr, const int* __restrict__ esrc,
    const float* __restrict__ eval, const ushort* __restrict__ x,
    ushort* __restrict__ zb, float* __restrict__ zf, int N, int out_f32) {
  int node = (blockIdx.x << 2) + (threadIdx.x >> 6);
  if (node >= N) return;
  const int lane = threadIdx.x & 63;
  const int h = lane >> 3;          // edge slot
  const int j = lane & 7;           // col oct: cols 8j..8j+7 (j<5 active)
  const bool act = (j < 5);

  int e   = row_ptr[node];
  int end = row_ptr[node + 1];

  float acc[8];
#pragma unroll
  for (int c = 0; c < 8; ++c) acc[c] = 0.f;

  // 16 edges per iteration: two independent gather chains
  for (; e + 16 <= end; e += 16) {
    int   s0 = esrc[e + h];
    int   s1 = esrc[e + 8 + h];
    float v0 = eval[e + h];
    float v1 = eval[e + 8 + h];
    if (act) {
      u32x4 a = *(const u32x4*)(x + (size_t)s0 * PAD_C + j * 8);
      u32x4 b = *(const u32x4*)(x + (size_t)s1 * PAD_C + j * 8);
      acc[0] = fmaf(v0, bf2f(a.x & 0xffffu), acc[0]);
      acc[1] = fmaf(v0, bf2f(a.x >> 16),     acc[1]);
      acc[2] = fmaf(v0, bf2f(a.y & 0xffffu), acc[2]);
      acc[3] = fmaf(v0, bf2f(a.y >> 16),     acc[3]);
      acc[4] = fmaf(v0, bf2f(a.z & 0xffffu), acc[4]);
      acc[5] = fmaf(v0, bf2f(a.z >> 16),     acc[5]);
      acc[6] = fmaf(v0, bf2f(a.w & 0xffffu), acc[6]);
      acc[7] = fmaf(v0, bf2f(a.w >> 16),     acc[7]);
      acc[0] = fmaf(v1, bf2f(b.x & 0xffffu), acc[0]);
      acc[1] = fmaf(v1, bf2f(b.x >> 16),     acc[1]);
      acc[2] = fmaf(v1, bf2f(b.y & 0xffffu), acc[2]);
      acc[3] = fmaf(v1, bf2f(b.y >> 16),     acc[3]);
      acc[4] = fmaf(v1, bf2f(b.z & 0xffffu), acc[4]);
      acc[5] = fmaf(v1, bf2f(b.z >> 16),     acc[5]);
      acc[6] = fmaf(v1, bf2f(b.w & 0xffffu), acc[6]);
      acc[7] = fmaf(v1, bf2f(b.w >> 16),     acc[7]);
    }
  }
  for (; e + 8 <= end; e += 8) {
    int   s = esrc[e + h];
    float v = eval[e + h];
    if (act) {
      u32x4 u = *(const u32x4*)(x + (size_t)s * PAD_C + j * 8);
      acc[0] = fmaf(v, bf2f(u.x & 0xffffu), acc[0]);
      acc[1] = fmaf(v, bf2f(u.x >> 16),     acc[1]);
      acc[2] = fmaf(v, bf2f(u.y & 0xffffu), acc[2]);
      acc[3] = fmaf(v, bf2f(u.y >> 16),     acc[3]);
      acc[4] = fmaf(v, bf2f(u.z & 0xffffu), acc[4]);
      acc[5] = fmaf(v, bf2f(u.z >> 16),     acc[5]);
      acc[6] = fmaf(v, bf2f(u.w & 0xffffu), acc[6]);
      acc[7] = fmaf(v, bf2f(u.w >> 16),     acc[7]);
    }
  }
  if (e < end) {                    // tail: clamp slots past the end, weight 0
    int ei = e + h;
    int ec = ei < end ? ei : end - 1;
    int   s  = esrc[ec];
    float v0 = eval[ec];
    float v  = ei < end ? v0 : 0.f;
    if (act) {
      u32x4 u = *(const u32x4*)(x + (size_t)s * PAD_C + j * 8);
      acc[0] = fmaf(v, bf2f(u.x & 0xffffu), acc[0]);
      acc[1] = fmaf(v, bf2f(u.x >> 16),     acc[1]);
      acc[2] = fmaf(v, bf2f(u.y & 0xffffu), acc[2]);
      acc[3] = fmaf(v, bf2f(u.y >> 16),     acc[3]);
      acc[4] = fmaf(v, bf2f(u.z & 0xffffu), acc[4]);
      acc[5] = fmaf(v, bf2f(u.z >> 16),     acc[5]);
      acc[6] = fmaf(v, bf2f(u.w & 0xffffu), acc[6]);
      acc[7] = fmaf(v, bf2f(u.w >> 16),     acc[7]);
    }
  }

  // reduce across the 8 edge slots (lane bits 3..5); partners share j
#pragma unroll
  for (int c = 0; c < 8; ++c) acc[c] += __shfl_xor(acc[c], 8);
#pragma unroll
  for (int c = 0; c < 8; ++c) acc[c] += __shfl_xor(acc[c], 16);
#pragma unroll
  for (int c = 0; c < 8; ++c) acc[c] += __shfl_xor(acc[c], 32);

  if (out_f32) {
    if (lane < 5) {                 // lanes 0..4: j=0..4 -> cols 0..39
      float4 o0 = {acc[0], acc[1], acc[2], acc[3]};
      float4 o1 = {acc[4], acc[5], acc[6], acc[7]};
      float* p = zf + (size_t)node * C_DIM + j * 8;
      *(float4*)(p + 0) = o0;
      *(float4*)(p + 4) = o1;
    }
  } else {
    if (lane < 5) {                 // lanes 0..4: j=0..4 -> cols 0..39
      uint4 p;
      p.x = (uint)f2bf(acc[0]) | ((uint)f2bf(acc[1]) << 16);
      p.y = (uint)f2bf(acc[2]) | ((uint)f2bf(acc[3]) << 16);
      p.z = (uint)f2bf(acc[4]) | ((uint)f2bf(acc[5]) << 16);
      p.w = (uint)f2bf(acc[6]) | ((uint)f2bf(acc[7]) << 16);
      *(uint4*)(zb + (size_t)node * PAD_C + j * 8) = p;
    }
  }
}

// ---------------------------------------------------------------------------
extern "C" void kernel_launch(void* const* d_in, const int* in_sizes, int n_in,
                              void* d_out, int out_size, void* d_ws, size_t ws_size,
                              hipStream_t stream) {
  const float* feat  = (const float*)d_in[0];
  const float* W1    = (const float*)d_in[1];
  const float* W2    = (const float*)d_in[2];
  const int*   esrc  = (const int*)d_in[3];
  const int*   edst  = (const int*)d_in[4];
  const float* evalp = (const float*)d_in[5];
  float* out = (float*)d_out;

  const int N = in_sizes[0] / IN_DIM;   // 100000
  const int E = in_sizes[3];            // 1600000

  // ws: z0 bf16 [N][40] | z1 bf16 [N][40] | w1t [128][256] | w2t [64][128] | row_ptr
  char* ws = (char*)d_ws;
  ushort* z0  = (ushort*)ws;
  ushort* z1  = (ushort*)(ws + (size_t)N * PAD_C * 2);
  ushort* w1t = (ushort*)(ws + (size_t)N * PAD_C * 4);
  ushort* w2t = w1t + IN_DIM * H_DIM;
  int* row_ptr = (int*)((char*)(w2t + W2_ROWS * H_DIM));

  setup_kernel<<<(N + 1 + 255) / 256, 256, 0, stream>>>(
      edst, E, row_ptr, N + 1, W1, W2, w1t, w2t);
  fused_dense_kernel<<<(N + BM - 1) / BM, 256, 0, stream>>>(feat, w1t, w2t, z0, N);
  spmm_kernel<<<(N + 3) / 4, 256, 0, stream>>>(row_ptr, esrc, evalp, z0, z1, nullptr, N, 0);
  spmm_kernel<<<(N + 3) / 4, 256, 0, stream>>>(row_ptr, esrc, evalp, z1, nullptr, out, N, 1);
}

// Round 4
// 290.479 us; speedup vs baseline: 1.0395x; 1.0395x over previous
//
#include <hip/hip_runtime.h>
#include <cstddef>
#include <cstdint>

#define IN_DIM 256
#define H_DIM  128
#define C_DIM  40
#define BM     128
#define LDH    136   // ushort stride, phase-2 h / w2 tiles (272 B rows, conflict-free)
#define PAD_C  40    // z row width in bf16 cols: 40 cols = 80 B
#define W2_ROWS 64   // w2t padded n-rows (two 32-col MFMA tiles)
#define STEP   512   // ushorts per (rb,ks) fragment slab: 64 lanes x 8 bf16
#define RBSLAB 8192  // ushorts per rb: 16 ks x STEP (16 KB)

typedef short bf16x8 __attribute__((ext_vector_type(8)));
typedef float f32x16 __attribute__((ext_vector_type(16)));
typedef uint  u32x4  __attribute__((ext_vector_type(4)));

__device__ __forceinline__ ushort f2bf(float f) {   // RNE fp32 -> bf16
  uint u = __builtin_bit_cast(uint, f);
  u += 0x7fffu + ((u >> 16) & 1u);
  return (ushort)(u >> 16);
}
__device__ __forceinline__ float bf2f(uint s) {     // low 16 bits -> f32
  uint u = s << 16;
  return __builtin_bit_cast(float, u);
}
// packed fp32x2 -> bf16x2 (HW cvt if available; manual RNE fallback)
__device__ __forceinline__ uint pack2bf(float a, float b) {
#if __has_builtin(__builtin_amdgcn_cvt_pk_bf16_f32)
  typedef __bf16 bf16v2 __attribute__((ext_vector_type(2)));
  bf16v2 r = __builtin_amdgcn_cvt_pk_bf16_f32(a, b);
  return __builtin_bit_cast(uint, r);
#else
  return (uint)f2bf(a) | ((uint)f2bf(b) << 16);
#endif
}

// ---------------------------------------------------------------------------
// Setup (one launch): feat -> feat_frag (bf16, MFMA-fragment order),
// W1 -> b_frag (bf16 fragment order), W2 -> w2t, CSR row_ptr.
// feat_frag[rb][ks][l] (ushort8) = feat[32rb + (l&31)][16ks + (l>>5)*8 .. +8]
// b_frag[tn][ks][l]    (ushort8) = W1[16ks + (l>>5)*8 + j][32tn + (l&31)]
// Feat range: each wave (rb, ks fixed) does 2 float4 loads/lane; lanes l and
// l+32 consume complementary halves of each 64-B sector -> sector-exact.
// ---------------------------------------------------------------------------
__global__ void setup_kernel(const int* __restrict__ dst, int E,
                             int* __restrict__ row_ptr, int n1,
                             const float* __restrict__ W1,
                             const float* __restrict__ W2,
                             const float* __restrict__ feat,
                             ushort* __restrict__ feat_frag,
                             ushort* __restrict__ b_frag,
                             ushort* __restrict__ w2t,
                             int N, int feat_items) {
  int tid = blockIdx.x * blockDim.x + threadIdx.x;
  if (tid < feat_items) {                       // feat -> fragment order
    int l = tid & 63, ks = (tid >> 6) & 15, rb = tid >> 10;
    int row = rb * 32 + (l & 31); if (row >= N) row = N - 1;
    int col = ks * 16 + ((l >> 5) << 3);
    const float4* p = (const float4*)(feat + (size_t)row * IN_DIM + col);
    float4 v0 = p[0], v1 = p[1];
    uint4 pk;
    pk.x = pack2bf(v0.x, v0.y);
    pk.y = pack2bf(v0.z, v0.w);
    pk.z = pack2bf(v1.x, v1.y);
    pk.w = pack2bf(v1.z, v1.w);
    *(uint4*)(feat_frag + (size_t)tid * 8) = pk;
    return;
  }
  int u = tid - feat_items;
  if (u < 4096) {                               // W1 -> b_frag fragment order
    int l = u & 63, ks = (u >> 6) & 15, tn = u >> 10;
    int n  = 32 * tn + (l & 31);
    int k0 = ks * 16 + ((l >> 5) << 3);
    ushort r[8];
#pragma unroll
    for (int j = 0; j < 8; ++j) r[j] = f2bf(W1[(k0 + j) * H_DIM + n]);
    *(uint4*)(b_frag + u * 8) = *(uint4*)r;
    return;
  }
  u -= 4096;
  if (u < W2_ROWS * H_DIM) {                    // W2 -> w2t (n-major, zero-pad)
    int n = u >> 7, k = u & 127;
    w2t[u] = (n < C_DIM) ? f2bf(W2[k * C_DIM + n]) : (ushort)0;
    return;
  }
  u -= W2_ROWS * H_DIM;
  if (u < n1) {                                 // CSR row_ptr (lower_bound)
    int lo = 0, hi = E;
    while (lo < hi) {
      int mid = (lo + hi) >> 1;
      if (dst[mid] < u) lo = mid + 1; else hi = mid;
    }
    row_ptr[u] = lo;
  }
}

// ---------------------------------------------------------------------------
// Fused dense MLP: z0[n][0:40] = relu(feat[n] @ W1) @ W2, bf16, row stride 40.
// Block 256 thr (4 waves), 128-node tile, 52224 B LDS -> 3 blocks/CU.
// GEMM1: barrier-free, LDS-free. A from feat_frag: ONE dwordx4/lane, 64
// lanes contiguous over 1 KB (8 cachelines/instr vs 32 for strided-row
// loads). B from b_frag (64 KB, L2-resident, same contiguity). Depth-2
// ping-pong with compile-time indices. No conversion in-loop (pre-done).
// Phase 2: relu(h) -> LDS rows, w2t -> LDS, GEMM2 via MFMA (unchanged).
// ---------------------------------------------------------------------------
__global__ __launch_bounds__(256, 3) void fused_dense_kernel(
    const ushort* __restrict__ feat_frag, const ushort* __restrict__ b_frag,
    const ushort* __restrict__ w2t, ushort* __restrict__ z0, int N) {
  // phase2 only: h [128][LDH] (34816 B) + w2 [64][LDH] (17408 B) = 52224 B
  __shared__ __align__(16) ushort smem[26112];

  const int t = threadIdx.x;
  const int w = t >> 6, l = t & 63;
  const int nb = blockIdx.x * BM;
  const int rb = blockIdx.x * 4 + w;            // 32-row block of this wave

  f32x16 acc[4];
#pragma unroll
  for (int tn = 0; tn < 4; ++tn)
#pragma unroll
    for (int r = 0; r < 16; ++r) acc[tn][r] = 0.f;

  const ushort* ap = feat_frag + (size_t)rb * RBSLAB + l * 8;
  const ushort* bp = b_frag + l * 8;

  bf16x8 Ax[2];
  bf16x8 Bx[2][4];
  Ax[0] = *(const bf16x8*)(ap);
#pragma unroll
  for (int tn = 0; tn < 4; ++tn)
    Bx[0][tn] = *(const bf16x8*)(bp + tn * (16 * STEP));

#pragma unroll
  for (int ks = 0; ks < 16; ++ks) {             // K = 256, 16 steps of 16
    const int c = ks & 1;
    if (ks < 15) {                              // prefetch next K-step
      Ax[c ^ 1] = *(const bf16x8*)(ap + (ks + 1) * STEP);
#pragma unroll
      for (int tn = 0; tn < 4; ++tn)
        Bx[c ^ 1][tn] = *(const bf16x8*)(bp + tn * (16 * STEP) + (ks + 1) * STEP);
    }
#pragma unroll
    for (int tn = 0; tn < 4; ++tn)
      acc[tn] = __builtin_amdgcn_mfma_f32_32x32x16_bf16(Ax[c], Bx[c][tn], acc[tn], 0, 0, 0);
  }

  // ---- phase 2: relu(h) -> LDS rows [node][k], C-layout: col=l&31, node=(r&3)+8*(r>>2)+4*(l>>5)
#pragma unroll
  for (int tn = 0; tn < 4; ++tn) {
    int col = tn * 32 + (l & 31);
#pragma unroll
    for (int r = 0; r < 16; ++r) {
      int nodeLoc = (r & 3) + 8 * (r >> 2) + 4 * (l >> 5) + 32 * w;
      float v = acc[tn][r];
      smem[nodeLoc * LDH + col] = f2bf(v > 0.f ? v : 0.f);
    }
  }
  // stage w2t [64][128] -> LDS [64][LDH]: thread t copies 32 ushorts (4 uint4)
  {
    int row = t >> 2, c4 = (t & 3) << 5;
    const uint4* src = (const uint4*)(w2t + row * H_DIM + c4);
    uint4* dst = (uint4*)(smem + 128 * LDH + row * LDH + c4);
    dst[0] = src[0];
    dst[1] = src[1];
    dst[2] = src[2];
    dst[3] = src[3];
  }
  __syncthreads();

  // GEMM2: wave w -> nodes 32w..+31, n-tiles {0..31, 32..63}, K=128
  f32x16 acc2[2];
#pragma unroll
  for (int tn = 0; tn < 2; ++tn)
#pragma unroll
    for (int r = 0; r < 16; ++r) acc2[tn][r] = 0.f;

  const ushort* Hbase  = smem + (w * 32 + (l & 31)) * LDH + ((l >> 5) << 3);
  const ushort* W2base = smem + 128 * LDH + (l & 31) * LDH + ((l >> 5) << 3);
#pragma unroll
  for (int kb = 0; kb < 8; ++kb) {
    bf16x8 af = *(const bf16x8*)(Hbase + kb * 16);
#pragma unroll
    for (int tn = 0; tn < 2; ++tn) {
      bf16x8 bfr = *(const bf16x8*)(W2base + tn * 32 * LDH + kb * 16);
      acc2[tn] = __builtin_amdgcn_mfma_f32_32x32x16_bf16(af, bfr, acc2[tn], 0, 0, 0);
    }
  }

  // store z0 cols 0..39 only (row stride PAD_C = 40)
#pragma unroll
  for (int tn = 0; tn < 2; ++tn) {
    int col = tn * 32 + (l & 31);
    if (col < C_DIM) {
#pragma unroll
      for (int r = 0; r < 16; ++r) {
        int node = nb + 32 * w + (r & 3) + 8 * (r >> 2) + 4 * (l >> 5);
        if (node < N) z0[(size_t)node * PAD_C + col] = f2bf(acc2[tn][r]);
      }
    }
  }
}

// ---------------------------------------------------------------------------
// SPMM (CSR, dst-sorted): one wave per node. lane = 8*h + j (h = edge slot,
// j = col oct). Rows are 40 bf16 cols = 80 B -> only lanes with j < 5
// gather/FMA. Main loop unrolled x2 (16 edges/iter). Butterfly-reduce slots.
// ---------------------------------------------------------------------------
__global__ __launch_bounds__(256) void spmm_kernel(
    const int* __restrict__ row_ptr, const int* __restrict__ esrc,
    const float* __restrict__ eval, const ushort* __restrict__ x,
    ushort* __restrict__ zb, float* __restrict__ zf, int N, int out_f32) {
  int node = (blockIdx.x << 2) + (threadIdx.x >> 6);
  if (node >= N) return;
  const int lane = threadIdx.x & 63;
  const int h = lane >> 3;          // edge slot
  const int j = lane & 7;           // col oct: cols 8j..8j+7 (j<5 active)
  const bool act = (j < 5);

  int e   = row_ptr[node];
  int end = row_ptr[node + 1];

  float acc[8];
#pragma unroll
  for (int c = 0; c < 8; ++c) acc[c] = 0.f;

  // 16 edges per iteration: two independent gather chains
  for (; e + 16 <= end; e += 16) {
    int   s0 = esrc[e + h];
    int   s1 = esrc[e + 8 + h];
    float v0 = eval[e + h];
    float v1 = eval[e + 8 + h];
    if (act) {
      u32x4 a = *(const u32x4*)(x + (size_t)s0 * PAD_C + j * 8);
      u32x4 b = *(const u32x4*)(x + (size_t)s1 * PAD_C + j * 8);
      acc[0] = fmaf(v0, bf2f(a.x & 0xffffu), acc[0]);
      acc[1] = fmaf(v0, bf2f(a.x >> 16),     acc[1]);
      acc[2] = fmaf(v0, bf2f(a.y & 0xffffu), acc[2]);
      acc[3] = fmaf(v0, bf2f(a.y >> 16),     acc[3]);
      acc[4] = fmaf(v0, bf2f(a.z & 0xffffu), acc[4]);
      acc[5] = fmaf(v0, bf2f(a.z >> 16),     acc[5]);
      acc[6] = fmaf(v0, bf2f(a.w & 0xffffu), acc[6]);
      acc[7] = fmaf(v0, bf2f(a.w >> 16),     acc[7]);
      acc[0] = fmaf(v1, bf2f(b.x & 0xffffu), acc[0]);
      acc[1] = fmaf(v1, bf2f(b.x >> 16),     acc[1]);
      acc[2] = fmaf(v1, bf2f(b.y & 0xffffu), acc[2]);
      acc[3] = fmaf(v1, bf2f(b.y >> 16),     acc[3]);
      acc[4] = fmaf(v1, bf2f(b.z & 0xffffu), acc[4]);
      acc[5] = fmaf(v1, bf2f(b.z >> 16),     acc[5]);
      acc[6] = fmaf(v1, bf2f(b.w & 0xffffu), acc[6]);
      acc[7] = fmaf(v1, bf2f(b.w >> 16),     acc[7]);
    }
  }
  for (; e + 8 <= end; e += 8) {
    int   s = esrc[e + h];
    float v = eval[e + h];
    if (act) {
      u32x4 u = *(const u32x4*)(x + (size_t)s * PAD_C + j * 8);
      acc[0] = fmaf(v, bf2f(u.x & 0xffffu), acc[0]);
      acc[1] = fmaf(v, bf2f(u.x >> 16),     acc[1]);
      acc[2] = fmaf(v, bf2f(u.y & 0xffffu), acc[2]);
      acc[3] = fmaf(v, bf2f(u.y >> 16),     acc[3]);
      acc[4] = fmaf(v, bf2f(u.z & 0xffffu), acc[4]);
      acc[5] = fmaf(v, bf2f(u.z >> 16),     acc[5]);
      acc[6] = fmaf(v, bf2f(u.w & 0xffffu), acc[6]);
      acc[7] = fmaf(v, bf2f(u.w >> 16),     acc[7]);
    }
  }
  if (e < end) {                    // tail: clamp slots past the end, weight 0
    int ei = e + h;
    int ec = ei < end ? ei : end - 1;
    int   s  = esrc[ec];
    float v0 = eval[ec];
    float v  = ei < end ? v0 : 0.f;
    if (act) {
      u32x4 u = *(const u32x4*)(x + (size_t)s * PAD_C + j * 8);
      acc[0] = fmaf(v, bf2f(u.x & 0xffffu), acc[0]);
      acc[1] = fmaf(v, bf2f(u.x >> 16),     acc[1]);
      acc[2] = fmaf(v, bf2f(u.y & 0xffffu), acc[2]);
      acc[3] = fmaf(v, bf2f(u.y >> 16),     acc[3]);
      acc[4] = fmaf(v, bf2f(u.z & 0xffffu), acc[4]);
      acc[5] = fmaf(v, bf2f(u.z >> 16),     acc[5]);
      acc[6] = fmaf(v, bf2f(u.w & 0xffffu), acc[6]);
      acc[7] = fmaf(v, bf2f(u.w >> 16),     acc[7]);
    }
  }

  // reduce across the 8 edge slots (lane bits 3..5); partners share j
#pragma unroll
  for (int c = 0; c < 8; ++c) acc[c] += __shfl_xor(acc[c], 8);
#pragma unroll
  for (int c = 0; c < 8; ++c) acc[c] += __shfl_xor(acc[c], 16);
#pragma unroll
  for (int c = 0; c < 8; ++c) acc[c] += __shfl_xor(acc[c], 32);

  if (out_f32) {
    if (lane < 5) {                 // lanes 0..4: j=0..4 -> cols 0..39
      float4 o0 = {acc[0], acc[1], acc[2], acc[3]};
      float4 o1 = {acc[4], acc[5], acc[6], acc[7]};
      float* p = zf + (size_t)node * C_DIM + j * 8;
      *(float4*)(p + 0) = o0;
      *(float4*)(p + 4) = o1;
    }
  } else {
    if (lane < 5) {                 // lanes 0..4: j=0..4 -> cols 0..39
      uint4 p;
      p.x = (uint)f2bf(acc[0]) | ((uint)f2bf(acc[1]) << 16);
      p.y = (uint)f2bf(acc[2]) | ((uint)f2bf(acc[3]) << 16);
      p.z = (uint)f2bf(acc[4]) | ((uint)f2bf(acc[5]) << 16);
      p.w = (uint)f2bf(acc[6]) | ((uint)f2bf(acc[7]) << 16);
      *(uint4*)(zb + (size_t)node * PAD_C + j * 8) = p;
    }
  }
}

// ---------------------------------------------------------------------------
extern "C" void kernel_launch(void* const* d_in, const int* in_sizes, int n_in,
                              void* d_out, int out_size, void* d_ws, size_t ws_size,
                              hipStream_t stream) {
  const float* feat  = (const float*)d_in[0];
  const float* W1    = (const float*)d_in[1];
  const float* W2    = (const float*)d_in[2];
  const int*   esrc  = (const int*)d_in[3];
  const int*   edst  = (const int*)d_in[4];
  const float* evalp = (const float*)d_in[5];
  float* out = (float*)d_out;

  const int N = in_sizes[0] / IN_DIM;   // 100000
  const int E = in_sizes[3];            // 1600000

  const int nblk  = (N + BM - 1) / BM;  // GEMM1 blocks
  const int rbmax = nblk * 4;           // 32-row blocks to materialize
  const int feat_items = rbmax * 1024;  // (rb, ks, lane) triples

  // ws: z0 bf16 [N][40] | z1 bf16 [N][40] | feat_frag | b_frag | w2t | row_ptr
  char* ws = (char*)d_ws;
  ushort* z0        = (ushort*)ws;
  ushort* z1        = (ushort*)(ws + (size_t)N * PAD_C * 2);
  ushort* feat_frag = (ushort*)(ws + (size_t)N * PAD_C * 4);
  ushort* b_frag    = feat_frag + (size_t)rbmax * RBSLAB;
  ushort* w2t       = b_frag + 4 * 16 * STEP;
  int* row_ptr      = (int*)(w2t + W2_ROWS * H_DIM);

  const int setup_items = feat_items + 4096 + W2_ROWS * H_DIM + (N + 1);
  setup_kernel<<<(setup_items + 255) / 256, 256, 0, stream>>>(
      edst, E, row_ptr, N + 1, W1, W2, feat, feat_frag, b_frag, w2t, N, feat_items);
  fused_dense_kernel<<<nblk, 256, 0, stream>>>(feat_frag, b_frag, w2t, z0, N);
  spmm_kernel<<<(N + 3) / 4, 256, 0, stream>>>(row_ptr, esrc, evalp, z0, z1, nullptr, N, 0);
  spmm_kernel<<<(N + 3) / 4, 256, 0, stream>>>(row_ptr, esrc, evalp, z1, nullptr, out, N, 1);
}

// Round 5
// 287.971 us; speedup vs baseline: 1.0485x; 1.0087x over previous
//
#include <hip/hip_runtime.h>
#include <cstddef>
#include <cstdint>

#define IN_DIM 256
#define H_DIM  128
#define C_DIM  40
#define BM     128
#define LDH    136   // ushort stride, phase-2 h / w2 tiles (272 B rows, conflict-free)
#define PAD_C  40    // z row width in bf16 cols: 40 cols = 80 B
#define W2_ROWS 64   // w2t padded n-rows (two 32-col MFMA tiles)
#define STEP   512   // ushorts per (rb,ks) fragment slab: 64 lanes x 8 bf16
#define RBSLAB 8192  // ushorts per rb: 16 ks x STEP (16 KB)
#define KSP    520   // padded ks-slab stride in LDS (ushorts): 1040 B, 16B-aligned

typedef short bf16x8 __attribute__((ext_vector_type(8)));
typedef float f32x16 __attribute__((ext_vector_type(16)));
typedef uint  u32x4  __attribute__((ext_vector_type(4)));

__device__ __forceinline__ ushort f2bf(float f) {   // RNE fp32 -> bf16
  uint u = __builtin_bit_cast(uint, f);
  u += 0x7fffu + ((u >> 16) & 1u);
  return (ushort)(u >> 16);
}
__device__ __forceinline__ float bf2f(uint s) {     // low 16 bits -> f32
  uint u = s << 16;
  return __builtin_bit_cast(float, u);
}
// packed fp32x2 -> bf16x2 (HW cvt if available; manual RNE fallback)
__device__ __forceinline__ uint pack2bf(float a, float b) {
#if __has_builtin(__builtin_amdgcn_cvt_pk_bf16_f32)
  typedef __bf16 bf16v2 __attribute__((ext_vector_type(2)));
  bf16v2 r = __builtin_amdgcn_cvt_pk_bf16_f32(a, b);
  return __builtin_bit_cast(uint, r);
#else
  return (uint)f2bf(a) | ((uint)f2bf(b) << 16);
#endif
}

// ---------------------------------------------------------------------------
// Setup (one launch, role by blockIdx):
//  blocks [0, rbmax):  feat -> feat_frag via LDS transpose.
//    Read COALESCED: lane l covers 32 contiguous bytes of a row (2 dwordx4;
//    16 B/lane/instr contiguous — the same shape the 6.8 TB/s fills use).
//    Scatter to fragment order happens in LDS (ks-slab stride 520 ushorts,
//    <=4-way write conflict, non-critical). Write out fully coalesced.
//  tail blocks: W1 -> b_frag (fragment order), W2 -> w2t, CSR row_ptr.
// feat_frag[rb][ks][l] (ushort8) = feat[32rb + (l&31)][16ks + (l>>5)*8 .. +8]
// b_frag[tn][ks][l]    (ushort8) = W1[16ks + (l>>5)*8 + j][32tn + (l&31)]
// ---------------------------------------------------------------------------
__global__ void setup_kernel(const int* __restrict__ dst, int E,
                             int* __restrict__ row_ptr, int n1,
                             const float* __restrict__ W1,
                             const float* __restrict__ W2,
                             const float* __restrict__ feat,
                             ushort* __restrict__ feat_frag,
                             ushort* __restrict__ b_frag,
                             ushort* __restrict__ w2t,
                             int N, int rbmax) {
  if ((int)blockIdx.x < rbmax) {                // feat transpose, one rb/block
    __shared__ __align__(16) ushort lds[16 * KSP];   // 16640 B
    const int rb = blockIdx.x;
    const int t  = threadIdx.x;
#pragma unroll
    for (int i = 0; i < 4; ++i) {
      int G = i * 256 + t;                      // 0..1023 granules (row, oct)
      int r = G >> 5;                           // row in rb (0..31)
      int m = G & 31;                           // col oct (8 floats)
      int row = rb * 32 + r; if (row >= N) row = N - 1;
      const float4* p = (const float4*)(feat + (size_t)row * IN_DIM + m * 8);
      float4 v0 = p[0], v1 = p[1];
      uint4 pk;
      pk.x = pack2bf(v0.x, v0.y);
      pk.y = pack2bf(v0.z, v0.w);
      pk.z = pack2bf(v1.x, v1.y);
      pk.w = pack2bf(v1.z, v1.w);
      int ks = m >> 1, hi = m & 1;              // fragment coords
      *(uint4*)(lds + ks * KSP + (r + 32 * hi) * 8) = pk;
    }
    __syncthreads();
#pragma unroll
    for (int i = 0; i < 4; ++i) {
      int G = i * 256 + t;                      // 0..1023 granules (ks, l)
      int ks = G >> 6, l = G & 63;
      *(uint4*)(feat_frag + (size_t)rb * RBSLAB + (size_t)G * 8) =
          *(const uint4*)(lds + ks * KSP + l * 8);
    }
    return;
  }
  int u = ((int)blockIdx.x - rbmax) * blockDim.x + threadIdx.x;
  if (u < 4096) {                               // W1 -> b_frag fragment order
    int l = u & 63, ks = (u >> 6) & 15, tn = u >> 10;
    int n  = 32 * tn + (l & 31);
    int k0 = ks * 16 + ((l >> 5) << 3);
    ushort r[8];
#pragma unroll
    for (int j = 0; j < 8; ++j) r[j] = f2bf(W1[(k0 + j) * H_DIM + n]);
    *(uint4*)(b_frag + u * 8) = *(uint4*)r;
    return;
  }
  u -= 4096;
  if (u < W2_ROWS * H_DIM) {                    // W2 -> w2t (n-major, zero-pad)
    int n = u >> 7, k = u & 127;
    w2t[u] = (n < C_DIM) ? f2bf(W2[k * C_DIM + n]) : (ushort)0;
    return;
  }
  u -= W2_ROWS * H_DIM;
  if (u < n1) {                                 // CSR row_ptr (lower_bound)
    int lo = 0, hi = E;
    while (lo < hi) {
      int mid = (lo + hi) >> 1;
      if (dst[mid] < u) lo = mid + 1; else hi = mid;
    }
    row_ptr[u] = lo;
  }
}

// ---------------------------------------------------------------------------
// Fused dense MLP: z0[n][0:40] = relu(feat[n] @ W1) @ W2, bf16, row stride 40.
// Block 256 thr (4 waves), 128-node tile, 52224 B LDS -> 3 blocks/CU.
// GEMM1: barrier-free, LDS-free. A from feat_frag: ONE dwordx4/lane, 64
// lanes contiguous over 1 KB. B from b_frag (64 KB, L2-resident, same
// contiguity). Depth-2 ping-pong with compile-time indices.
// Phase 2: relu(h) -> LDS rows, w2t -> LDS, GEMM2 via MFMA (unchanged).
// ---------------------------------------------------------------------------
__global__ __launch_bounds__(256, 3) void fused_dense_kernel(
    const ushort* __restrict__ feat_frag, const ushort* __restrict__ b_frag,
    const ushort* __restrict__ w2t, ushort* __restrict__ z0, int N) {
  // phase2 only: h [128][LDH] (34816 B) + w2 [64][LDH] (17408 B) = 52224 B
  __shared__ __align__(16) ushort smem[26112];

  const int t = threadIdx.x;
  const int w = t >> 6, l = t & 63;
  const int nb = blockIdx.x * BM;
  const int rb = blockIdx.x * 4 + w;            // 32-row block of this wave

  f32x16 acc[4];
#pragma unroll
  for (int tn = 0; tn < 4; ++tn)
#pragma unroll
    for (int r = 0; r < 16; ++r) acc[tn][r] = 0.f;

  const ushort* ap = feat_frag + (size_t)rb * RBSLAB + l * 8;
  const ushort* bp = b_frag + l * 8;

  bf16x8 Ax[2];
  bf16x8 Bx[2][4];
  Ax[0] = *(const bf16x8*)(ap);
#pragma unroll
  for (int tn = 0; tn < 4; ++tn)
    Bx[0][tn] = *(const bf16x8*)(bp + tn * (16 * STEP));

#pragma unroll
  for (int ks = 0; ks < 16; ++ks) {             // K = 256, 16 steps of 16
    const int c = ks & 1;
    if (ks < 15) {                              // prefetch next K-step
      Ax[c ^ 1] = *(const bf16x8*)(ap + (ks + 1) * STEP);
#pragma unroll
      for (int tn = 0; tn < 4; ++tn)
        Bx[c ^ 1][tn] = *(const bf16x8*)(bp + tn * (16 * STEP) + (ks + 1) * STEP);
    }
#pragma unroll
    for (int tn = 0; tn < 4; ++tn)
      acc[tn] = __builtin_amdgcn_mfma_f32_32x32x16_bf16(Ax[c], Bx[c][tn], acc[tn], 0, 0, 0);
  }

  // ---- phase 2: relu(h) -> LDS rows [node][k], C-layout: col=l&31, node=(r&3)+8*(r>>2)+4*(l>>5)
#pragma unroll
  for (int tn = 0; tn < 4; ++tn) {
    int col = tn * 32 + (l & 31);
#pragma unroll
    for (int r = 0; r < 16; ++r) {
      int nodeLoc = (r & 3) + 8 * (r >> 2) + 4 * (l >> 5) + 32 * w;
      float v = acc[tn][r];
      smem[nodeLoc * LDH + col] = f2bf(v > 0.f ? v : 0.f);
    }
  }
  // stage w2t [64][128] -> LDS [64][LDH]: thread t copies 32 ushorts (4 uint4)
  {
    int row = t >> 2, c4 = (t & 3) << 5;
    const uint4* src = (const uint4*)(w2t + row * H_DIM + c4);
    uint4* dst = (uint4*)(smem + 128 * LDH + row * LDH + c4);
    dst[0] = src[0];
    dst[1] = src[1];
    dst[2] = src[2];
    dst[3] = src[3];
  }
  __syncthreads();

  // GEMM2: wave w -> nodes 32w..+31, n-tiles {0..31, 32..63}, K=128
  f32x16 acc2[2];
#pragma unroll
  for (int tn = 0; tn < 2; ++tn)
#pragma unroll
    for (int r = 0; r < 16; ++r) acc2[tn][r] = 0.f;

  const ushort* Hbase  = smem + (w * 32 + (l & 31)) * LDH + ((l >> 5) << 3);
  const ushort* W2base = smem + 128 * LDH + (l & 31) * LDH + ((l >> 5) << 3);
#pragma unroll
  for (int kb = 0; kb < 8; ++kb) {
    bf16x8 af = *(const bf16x8*)(Hbase + kb * 16);
#pragma unroll
    for (int tn = 0; tn < 2; ++tn) {
      bf16x8 bfr = *(const bf16x8*)(W2base + tn * 32 * LDH + kb * 16);
      acc2[tn] = __builtin_amdgcn_mfma_f32_32x32x16_bf16(af, bfr, acc2[tn], 0, 0, 0);
    }
  }

  // store z0 cols 0..39 only (row stride PAD_C = 40)
#pragma unroll
  for (int tn = 0; tn < 2; ++tn) {
    int col = tn * 32 + (l & 31);
    if (col < C_DIM) {
#pragma unroll
      for (int r = 0; r < 16; ++r) {
        int node = nb + 32 * w + (r & 3) + 8 * (r >> 2) + 4 * (l >> 5);
        if (node < N) z0[(size_t)node * PAD_C + col] = f2bf(acc2[tn][r]);
      }
    }
  }
}

// ---------------------------------------------------------------------------
// SPMM (CSR, dst-sorted): one wave per node. lane = 8*h + j (h = edge slot,
// j = col oct). Rows are 40 bf16 cols = 80 B -> only lanes with j < 5
// gather/FMA. Main loop unrolled x2 (16 edges/iter). Butterfly-reduce slots.
// ---------------------------------------------------------------------------
__global__ __launch_bounds__(256) void spmm_kernel(
    const int* __restrict__ row_ptr, const int* __restrict__ esrc,
    const float* __restrict__ eval, const ushort* __restrict__ x,
    ushort* __restrict__ zb, float* __restrict__ zf, int N, int out_f32) {
  int node = (blockIdx.x << 2) + (threadIdx.x >> 6);
  if (node >= N) return;
  const int lane = threadIdx.x & 63;
  const int h = lane >> 3;          // edge slot
  const int j = lane & 7;           // col oct: cols 8j..8j+7 (j<5 active)
  const bool act = (j < 5);

  int e   = row_ptr[node];
  int end = row_ptr[node + 1];

  float acc[8];
#pragma unroll
  for (int c = 0; c < 8; ++c) acc[c] = 0.f;

  // 16 edges per iteration: two independent gather chains
  for (; e + 16 <= end; e += 16) {
    int   s0 = esrc[e + h];
    int   s1 = esrc[e + 8 + h];
    float v0 = eval[e + h];
    float v1 = eval[e + 8 + h];
    if (act) {
      u32x4 a = *(const u32x4*)(x + (size_t)s0 * PAD_C + j * 8);
      u32x4 b = *(const u32x4*)(x + (size_t)s1 * PAD_C + j * 8);
      acc[0] = fmaf(v0, bf2f(a.x & 0xffffu), acc[0]);
      acc[1] = fmaf(v0, bf2f(a.x >> 16),     acc[1]);
      acc[2] = fmaf(v0, bf2f(a.y & 0xffffu), acc[2]);
      acc[3] = fmaf(v0, bf2f(a.y >> 16),     acc[3]);
      acc[4] = fmaf(v0, bf2f(a.z & 0xffffu), acc[4]);
      acc[5] = fmaf(v0, bf2f(a.z >> 16),     acc[5]);
      acc[6] = fmaf(v0, bf2f(a.w & 0xffffu), acc[6]);
      acc[7] = fmaf(v0, bf2f(a.w >> 16),     acc[7]);
      acc[0] = fmaf(v1, bf2f(b.x & 0xffffu), acc[0]);
      acc[1] = fmaf(v1, bf2f(b.x >> 16),     acc[1]);
      acc[2] = fmaf(v1, bf2f(b.y & 0xffffu), acc[2]);
      acc[3] = fmaf(v1, bf2f(b.y >> 16),     acc[3]);
      acc[4] = fmaf(v1, bf2f(b.z & 0xffffu), acc[4]);
      acc[5] = fmaf(v1, bf2f(b.z >> 16),     acc[5]);
      acc[6] = fmaf(v1, bf2f(b.w & 0xffffu), acc[6]);
      acc[7] = fmaf(v1, bf2f(b.w >> 16),     acc[7]);
    }
  }
  for (; e + 8 <= end; e += 8) {
    int   s = esrc[e + h];
    float v = eval[e + h];
    if (act) {
      u32x4 u = *(const u32x4*)(x + (size_t)s * PAD_C + j * 8);
      acc[0] = fmaf(v, bf2f(u.x & 0xffffu), acc[0]);
      acc[1] = fmaf(v, bf2f(u.x >> 16),     acc[1]);
      acc[2] = fmaf(v, bf2f(u.y & 0xffffu), acc[2]);
      acc[3] = fmaf(v, bf2f(u.y >> 16),     acc[3]);
      acc[4] = fmaf(v, bf2f(u.z & 0xffffu), acc[4]);
      acc[5] = fmaf(v, bf2f(u.z >> 16),     acc[5]);
      acc[6] = fmaf(v, bf2f(u.w & 0xffffu), acc[6]);
      acc[7] = fmaf(v, bf2f(u.w >> 16),     acc[7]);
    }
  }
  if (e < end) {                    // tail: clamp slots past the end, weight 0
    int ei = e + h;
    int ec = ei < end ? ei : end - 1;
    int   s  = esrc[ec];
    float v0 = eval[ec];
    float v  = ei < end ? v0 : 0.f;
    if (act) {
      u32x4 u = *(const u32x4*)(x + (size_t)s * PAD_C + j * 8);
      acc[0] = fmaf(v, bf2f(u.x & 0xffffu), acc[0]);
      acc[1] = fmaf(v, bf2f(u.x >> 16),     acc[1]);
      acc[2] = fmaf(v, bf2f(u.y & 0xffffu), acc[2]);
      acc[3] = fmaf(v, bf2f(u.y >> 16),     acc[3]);
      acc[4] = fmaf(v, bf2f(u.z & 0xffffu), acc[4]);
      acc[5] = fmaf(v, bf2f(u.z >> 16),     acc[5]);
      acc[6] = fmaf(v, bf2f(u.w & 0xffffu), acc[6]);
      acc[7] = fmaf(v, bf2f(u.w >> 16),     acc[7]);
    }
  }

  // reduce across the 8 edge slots (lane bits 3..5); partners share j
#pragma unroll
  for (int c = 0; c < 8; ++c) acc[c] += __shfl_xor(acc[c], 8);
#pragma unroll
  for (int c = 0; c < 8; ++c) acc[c] += __shfl_xor(acc[c], 16);
#pragma unroll
  for (int c = 0; c < 8; ++c) acc[c] += __shfl_xor(acc[c], 32);

  if (out_f32) {
    if (lane < 5) {                 // lanes 0..4: j=0..4 -> cols 0..39
      float4 o0 = {acc[0], acc[1], acc[2], acc[3]};
      float4 o1 = {acc[4], acc[5], acc[6], acc[7]};
      float* p = zf + (size_t)node * C_DIM + j * 8;
      *(float4*)(p + 0) = o0;
      *(float4*)(p + 4) = o1;
    }
  } else {
    if (lane < 5) {                 // lanes 0..4: j=0..4 -> cols 0..39
      uint4 p;
      p.x = (uint)f2bf(acc[0]) | ((uint)f2bf(acc[1]) << 16);
      p.y = (uint)f2bf(acc[2]) | ((uint)f2bf(acc[3]) << 16);
      p.z = (uint)f2bf(acc[4]) | ((uint)f2bf(acc[5]) << 16);
      p.w = (uint)f2bf(acc[6]) | ((uint)f2bf(acc[7]) << 16);
      *(uint4*)(zb + (size_t)node * PAD_C + j * 8) = p;
    }
  }
}

// ---------------------------------------------------------------------------
extern "C" void kernel_launch(void* const* d_in, const int* in_sizes, int n_in,
                              void* d_out, int out_size, void* d_ws, size_t ws_size,
                              hipStream_t stream) {
  const float* feat  = (const float*)d_in[0];
  const float* W1    = (const float*)d_in[1];
  const float* W2    = (const float*)d_in[2];
  const int*   esrc  = (const int*)d_in[3];
  const int*   edst  = (const int*)d_in[4];
  const float* evalp = (const float*)d_in[5];
  float* out = (float*)d_out;

  const int N = in_sizes[0] / IN_DIM;   // 100000
  const int E = in_sizes[3];            // 1600000

  const int nblk  = (N + BM - 1) / BM;  // GEMM1 blocks
  const int rbmax = nblk * 4;           // 32-row blocks to materialize
  const int feat_items = rbmax * 1024;  // (rb, ks, lane) triples
  (void)feat_items;

  // ws: z0 bf16 [N][40] | z1 bf16 [N][40] | feat_frag | b_frag | w2t | row_ptr
  char* ws = (char*)d_ws;
  ushort* z0        = (ushort*)ws;
  ushort* z1        = (ushort*)(ws + (size_t)N * PAD_C * 2);
  ushort* feat_frag = (ushort*)(ws + (size_t)N * PAD_C * 4);
  ushort* b_frag    = feat_frag + (size_t)rbmax * RBSLAB;
  ushort* w2t       = b_frag + 4 * 16 * STEP;
  int* row_ptr      = (int*)(w2t + W2_ROWS * H_DIM);

  const int tail_items  = 4096 + W2_ROWS * H_DIM + (N + 1);
  const int tail_blocks = (tail_items + 255) / 256;
  setup_kernel<<<rbmax + tail_blocks, 256, 0, stream>>>(
      edst, E, row_ptr, N + 1, W1, W2, feat, feat_frag, b_frag, w2t, N, rbmax);
  fused_dense_kernel<<<nblk, 256, 0, stream>>>(feat_frag, b_frag, w2t, z0, N);
  spmm_kernel<<<(N + 3) / 4, 256, 0, stream>>>(row_ptr, esrc, evalp, z0, z1, nullptr, N, 0);
  spmm_kernel<<<(N + 3) / 4, 256, 0, stream>>>(row_ptr, esrc, evalp, z1, nullptr, out, N, 1);
}

// Round 6
// 275.332 us; speedup vs baseline: 1.0967x; 1.0459x over previous
//
#include <hip/hip_runtime.h>
#include <cstddef>
#include <cstdint>

#define IN_DIM 256
#define H_DIM  128
#define C_DIM  40
#define BM     128
#define LDA    264   // ushort stride of A-tile rows in LDS (528 B, 16B-aligned)
#define LDH    136   // ushort stride, phase-2 h / w2 tiles (272 B rows, conflict-free)
#define PAD_C  40    // z row width in bf16 cols: 40 cols = 80 B
#define W2_ROWS 64   // w2t padded n-rows (two 32-col MFMA tiles)
#define STEP   512   // ushorts per ks slab of b_frag: 64 lanes x 8 bf16

typedef short bf16x8 __attribute__((ext_vector_type(8)));
typedef float f32x16 __attribute__((ext_vector_type(16)));
typedef uint  u32x4  __attribute__((ext_vector_type(4)));

__device__ __forceinline__ ushort f2bf(float f) {   // RNE fp32 -> bf16
  uint u = __builtin_bit_cast(uint, f);
  u += 0x7fffu + ((u >> 16) & 1u);
  return (ushort)(u >> 16);
}
__device__ __forceinline__ float bf2f(uint s) {     // low 16 bits -> f32
  uint u = s << 16;
  return __builtin_bit_cast(float, u);
}
// packed fp32x2 -> bf16x2 (HW cvt if available; manual RNE fallback)
__device__ __forceinline__ uint pack2bf(float a, float b) {
#if __has_builtin(__builtin_amdgcn_cvt_pk_bf16_f32)
  typedef __bf16 bf16v2 __attribute__((ext_vector_type(2)));
  bf16v2 r = __builtin_amdgcn_cvt_pk_bf16_f32(a, b);
  return __builtin_bit_cast(uint, r);
#else
  return (uint)f2bf(a) | ((uint)f2bf(b) << 16);
#endif
}

// ---------------------------------------------------------------------------
// Setup (one launch):
//  tid < E:      CSR row_ptr via boundary scan of sorted dst (coalesced O(E),
//                replaces 100K divergent binary searches).
//  next 4096:    W1 -> b_frag (MFMA fragment order).
//  next 8192:    W2 -> w2t (n-major, zero-padded n=40..63).
// b_frag[tn][ks][l] (ushort8) = W1[16ks + (l>>5)*8 + j][32tn + (l&31)]
// ---------------------------------------------------------------------------
__global__ void setup_kernel(const int* __restrict__ dst, int E,
                             int* __restrict__ row_ptr, int N,
                             const float* __restrict__ W1,
                             const float* __restrict__ W2,
                             ushort* __restrict__ b_frag,
                             ushort* __restrict__ w2t) {
  int tid = blockIdx.x * blockDim.x + threadIdx.x;
  if (tid < E) {
    int d1 = dst[tid];
    int d0 = (tid == 0) ? -1 : dst[tid - 1];
    for (int v = d0 + 1; v <= d1; ++v) row_ptr[v] = tid;
    if (tid == E - 1)
      for (int v = d1 + 1; v <= N; ++v) row_ptr[v] = E;
    return;
  }
  int u = tid - E;
  if (u < 4096) {                               // W1 -> b_frag fragment order
    int l = u & 63, ks = (u >> 6) & 15, tn = u >> 10;
    int n  = 32 * tn + (l & 31);
    int k0 = ks * 16 + ((l >> 5) << 3);
    ushort r[8];
#pragma unroll
    for (int j = 0; j < 8; ++j) r[j] = f2bf(W1[(k0 + j) * H_DIM + n]);
    *(uint4*)(b_frag + u * 8) = *(uint4*)r;
    return;
  }
  u -= 4096;
  if (u < W2_ROWS * H_DIM) {                    // W2 -> w2t (n-major, zero-pad)
    int n = u >> 7, k = u & 127;
    w2t[u] = (n < C_DIM) ? f2bf(W2[k * C_DIM + n]) : (ushort)0;
  }
}

// ---------------------------------------------------------------------------
// Fused dense MLP: z0[n][0:40] = relu(feat[n] @ W1) @ W2, bf16, row stride 40.
// Block 256 thr (4 waves), 128-node tile, 67584 B LDS -> 2 blocks/CU.
// Stage: whole 128x256 A-tile -> LDS as bf16 in ONE pass. Wave w, chunk c
// reads row 4c+w FULLY CONTIGUOUSLY (64 lanes x 16 B = 1 KB/instr — the
// 6.8 TB/s fill-kernel shape). feat is read exactly once, straight from HBM.
// One barrier, then 16 MFMA K-steps: A-fragments from LDS (stride 264,
// ~4-way conflicts on tiny volume), B from L2-resident b_frag (global,
// depth-2 ping-pong). Phase 2 aliases the same LDS after a barrier.
// ---------------------------------------------------------------------------
__global__ __launch_bounds__(256, 2) void fused_dense_kernel(
    const float* __restrict__ feat, const ushort* __restrict__ b_frag,
    const ushort* __restrict__ w2t, ushort* __restrict__ z0, int N) {
  // A-tile [128][LDA] = 33792 ushorts; phase2 h[128][LDH]+w2[64][LDH] = 26112
  __shared__ __align__(16) ushort smem[128 * LDA];

  const int t = threadIdx.x;
  const int w = t >> 6, l = t & 63;
  const int nb = blockIdx.x * BM;

  f32x16 acc[4];
#pragma unroll
  for (int tn = 0; tn < 4; ++tn)
#pragma unroll
    for (int r = 0; r < 16; ++r) acc[tn][r] = 0.f;

  const ushort* bp = b_frag + l * 8;
  bf16x8 Bx[2][4];
#pragma unroll
  for (int tn = 0; tn < 4; ++tn)
    Bx[0][tn] = *(const bf16x8*)(bp + tn * (16 * STEP));

  // ---- stage A-tile: wave w, chunk c -> row 4c+w, lane l -> 16 B slot l
#pragma unroll
  for (int c = 0; c < 32; ++c) {
    int row = 4 * c + w;
    int grow = nb + row; if (grow >= N) grow = N - 1;
    float4 v = *(const float4*)(feat + (size_t)grow * IN_DIM + l * 4);
    uint2 pk;
    pk.x = pack2bf(v.x, v.y);
    pk.y = pack2bf(v.z, v.w);
    *(uint2*)(smem + row * LDA + l * 4) = pk;
  }
  __syncthreads();

  // ---- GEMM1: 16 K-steps, A from LDS, B ping-pong from global (L2)
  const ushort* Abase = smem + (w * 32 + (l & 31)) * LDA + ((l >> 5) << 3);
#pragma unroll
  for (int ks = 0; ks < 16; ++ks) {
    const int c = ks & 1;
    if (ks < 15) {                              // prefetch next B K-step
#pragma unroll
      for (int tn = 0; tn < 4; ++tn)
        Bx[c ^ 1][tn] = *(const bf16x8*)(bp + tn * (16 * STEP) + (ks + 1) * STEP);
    }
    bf16x8 af = *(const bf16x8*)(Abase + ks * 16);
#pragma unroll
    for (int tn = 0; tn < 4; ++tn)
      acc[tn] = __builtin_amdgcn_mfma_f32_32x32x16_bf16(af, Bx[c][tn], acc[tn], 0, 0, 0);
  }
  __syncthreads();                              // all waves done reading A-tile

  // ---- phase 2: relu(h) -> LDS rows [node][k], C-layout: col=l&31, node=(r&3)+8*(r>>2)+4*(l>>5)
#pragma unroll
  for (int tn = 0; tn < 4; ++tn) {
    int col = tn * 32 + (l & 31);
#pragma unroll
    for (int r = 0; r < 16; ++r) {
      int nodeLoc = (r & 3) + 8 * (r >> 2) + 4 * (l >> 5) + 32 * w;
      float v = acc[tn][r];
      smem[nodeLoc * LDH + col] = f2bf(v > 0.f ? v : 0.f);
    }
  }
  // stage w2t [64][128] -> LDS [64][LDH]: thread t copies 32 ushorts (4 uint4)
  {
    int row = t >> 2, c4 = (t & 3) << 5;
    const uint4* src = (const uint4*)(w2t + row * H_DIM + c4);
    uint4* dst = (uint4*)(smem + 128 * LDH + row * LDH + c4);
    dst[0] = src[0];
    dst[1] = src[1];
    dst[2] = src[2];
    dst[3] = src[3];
  }
  __syncthreads();

  // GEMM2: wave w -> nodes 32w..+31, n-tiles {0..31, 32..63}, K=128
  f32x16 acc2[2];
#pragma unroll
  for (int tn = 0; tn < 2; ++tn)
#pragma unroll
    for (int r = 0; r < 16; ++r) acc2[tn][r] = 0.f;

  const ushort* Hbase  = smem + (w * 32 + (l & 31)) * LDH + ((l >> 5) << 3);
  const ushort* W2base = smem + 128 * LDH + (l & 31) * LDH + ((l >> 5) << 3);
#pragma unroll
  for (int kb = 0; kb < 8; ++kb) {
    bf16x8 af = *(const bf16x8*)(Hbase + kb * 16);
#pragma unroll
    for (int tn = 0; tn < 2; ++tn) {
      bf16x8 bfr = *(const bf16x8*)(W2base + tn * 32 * LDH + kb * 16);
      acc2[tn] = __builtin_amdgcn_mfma_f32_32x32x16_bf16(af, bfr, acc2[tn], 0, 0, 0);
    }
  }

  // store z0 cols 0..39 only (row stride PAD_C = 40)
#pragma unroll
  for (int tn = 0; tn < 2; ++tn) {
    int col = tn * 32 + (l & 31);
    if (col < C_DIM) {
#pragma unroll
      for (int r = 0; r < 16; ++r) {
        int node = nb + 32 * w + (r & 3) + 8 * (r >> 2) + 4 * (l >> 5);
        if (node < N) z0[(size_t)node * PAD_C + col] = f2bf(acc2[tn][r]);
      }
    }
  }
}

// ---------------------------------------------------------------------------
// SPMM (CSR, dst-sorted): one wave per node. lane = 8*h + j (h = edge slot,
// j = col oct). Rows are 40 bf16 cols = 80 B -> only lanes with j < 5
// gather/FMA. Main loop unrolled x2 (16 edges/iter). Butterfly-reduce slots.
// ---------------------------------------------------------------------------
__global__ __launch_bounds__(256) void spmm_kernel(
    const int* __restrict__ row_ptr, const int* __restrict__ esrc,
    const float* __restrict__ eval, const ushort* __restrict__ x,
    ushort* __restrict__ zb, float* __restrict__ zf, int N, int out_f32) {
  int node = (blockIdx.x << 2) + (threadIdx.x >> 6);
  if (node >= N) return;
  const int lane = threadIdx.x & 63;
  const int h = lane >> 3;          // edge slot
  const int j = lane & 7;           // col oct: cols 8j..8j+7 (j<5 active)
  const bool act = (j < 5);

  int e   = row_ptr[node];
  int end = row_ptr[node + 1];

  float acc[8];
#pragma unroll
  for (int c = 0; c < 8; ++c) acc[c] = 0.f;

  // 16 edges per iteration: two independent gather chains
  for (; e + 16 <= end; e += 16) {
    int   s0 = esrc[e + h];
    int   s1 = esrc[e + 8 + h];
    float v0 = eval[e + h];
    float v1 = eval[e + 8 + h];
    if (act) {
      u32x4 a = *(const u32x4*)(x + (size_t)s0 * PAD_C + j * 8);
      u32x4 b = *(const u32x4*)(x + (size_t)s1 * PAD_C + j * 8);
      acc[0] = fmaf(v0, bf2f(a.x & 0xffffu), acc[0]);
      acc[1] = fmaf(v0, bf2f(a.x >> 16),     acc[1]);
      acc[2] = fmaf(v0, bf2f(a.y & 0xffffu), acc[2]);
      acc[3] = fmaf(v0, bf2f(a.y >> 16),     acc[3]);
      acc[4] = fmaf(v0, bf2f(a.z & 0xffffu), acc[4]);
      acc[5] = fmaf(v0, bf2f(a.z >> 16),     acc[5]);
      acc[6] = fmaf(v0, bf2f(a.w & 0xffffu), acc[6]);
      acc[7] = fmaf(v0, bf2f(a.w >> 16),     acc[7]);
      acc[0] = fmaf(v1, bf2f(b.x & 0xffffu), acc[0]);
      acc[1] = fmaf(v1, bf2f(b.x >> 16),     acc[1]);
      acc[2] = fmaf(v1, bf2f(b.y & 0xffffu), acc[2]);
      acc[3] = fmaf(v1, bf2f(b.y >> 16),     acc[3]);
      acc[4] = fmaf(v1, bf2f(b.z & 0xffffu), acc[4]);
      acc[5] = fmaf(v1, bf2f(b.z >> 16),     acc[5]);
      acc[6] = fmaf(v1, bf2f(b.w & 0xffffu), acc[6]);
      acc[7] = fmaf(v1, bf2f(b.w >> 16),     acc[7]);
    }
  }
  for (; e + 8 <= end; e += 8) {
    int   s = esrc[e + h];
    float v = eval[e + h];
    if (act) {
      u32x4 u = *(const u32x4*)(x + (size_t)s * PAD_C + j * 8);
      acc[0] = fmaf(v, bf2f(u.x & 0xffffu), acc[0]);
      acc[1] = fmaf(v, bf2f(u.x >> 16),     acc[1]);
      acc[2] = fmaf(v, bf2f(u.y & 0xffffu), acc[2]);
      acc[3] = fmaf(v, bf2f(u.y >> 16),     acc[3]);
      acc[4] = fmaf(v, bf2f(u.z & 0xffffu), acc[4]);
      acc[5] = fmaf(v, bf2f(u.z >> 16),     acc[5]);
      acc[6] = fmaf(v, bf2f(u.w & 0xffffu), acc[6]);
      acc[7] = fmaf(v, bf2f(u.w >> 16),     acc[7]);
    }
  }
  if (e < end) {                    // tail: clamp slots past the end, weight 0
    int ei = e + h;
    int ec = ei < end ? ei : end - 1;
    int   s  = esrc[ec];
    float v0 = eval[ec];
    float v  = ei < end ? v0 : 0.f;
    if (act) {
      u32x4 u = *(const u32x4*)(x + (size_t)s * PAD_C + j * 8);
      acc[0] = fmaf(v, bf2f(u.x & 0xffffu), acc[0]);
      acc[1] = fmaf(v, bf2f(u.x >> 16),     acc[1]);
      acc[2] = fmaf(v, bf2f(u.y & 0xffffu), acc[2]);
      acc[3] = fmaf(v, bf2f(u.y >> 16),     acc[3]);
      acc[4] = fmaf(v, bf2f(u.z & 0xffffu), acc[4]);
      acc[5] = fmaf(v, bf2f(u.z >> 16),     acc[5]);
      acc[6] = fmaf(v, bf2f(u.w & 0xffffu), acc[6]);
      acc[7] = fmaf(v, bf2f(u.w >> 16),     acc[7]);
    }
  }

  // reduce across the 8 edge slots (lane bits 3..5); partners share j
#pragma unroll
  for (int c = 0; c < 8; ++c) acc[c] += __shfl_xor(acc[c], 8);
#pragma unroll
  for (int c = 0; c < 8; ++c) acc[c] += __shfl_xor(acc[c], 16);
#pragma unroll
  for (int c = 0; c < 8; ++c) acc[c] += __shfl_xor(acc[c], 32);

  if (out_f32) {
    if (lane < 5) {                 // lanes 0..4: j=0..4 -> cols 0..39
      float4 o0 = {acc[0], acc[1], acc[2], acc[3]};
      float4 o1 = {acc[4], acc[5], acc[6], acc[7]};
      float* p = zf + (size_t)node * C_DIM + j * 8;
      *(float4*)(p + 0) = o0;
      *(float4*)(p + 4) = o1;
    }
  } else {
    if (lane < 5) {                 // lanes 0..4: j=0..4 -> cols 0..39
      uint4 p;
      p.x = (uint)f2bf(acc[0]) | ((uint)f2bf(acc[1]) << 16);
      p.y = (uint)f2bf(acc[2]) | ((uint)f2bf(acc[3]) << 16);
      p.z = (uint)f2bf(acc[4]) | ((uint)f2bf(acc[5]) << 16);
      p.w = (uint)f2bf(acc[6]) | ((uint)f2bf(acc[7]) << 16);
      *(uint4*)(zb + (size_t)node * PAD_C + j * 8) = p;
    }
  }
}

// ---------------------------------------------------------------------------
extern "C" void kernel_launch(void* const* d_in, const int* in_sizes, int n_in,
                              void* d_out, int out_size, void* d_ws, size_t ws_size,
                              hipStream_t stream) {
  const float* feat  = (const float*)d_in[0];
  const float* W1    = (const float*)d_in[1];
  const float* W2    = (const float*)d_in[2];
  const int*   esrc  = (const int*)d_in[3];
  const int*   edst  = (const int*)d_in[4];
  const float* evalp = (const float*)d_in[5];
  float* out = (float*)d_out;

  const int N = in_sizes[0] / IN_DIM;   // 100000
  const int E = in_sizes[3];            // 1600000

  const int nblk = (N + BM - 1) / BM;   // GEMM1 blocks

  // ws: z0 bf16 [N][40] | z1 bf16 [N][40] | b_frag | w2t | row_ptr
  char* ws = (char*)d_ws;
  ushort* z0     = (ushort*)ws;
  ushort* z1     = (ushort*)(ws + (size_t)N * PAD_C * 2);
  ushort* b_frag = (ushort*)(ws + (size_t)N * PAD_C * 4);
  ushort* w2t    = b_frag + 4 * 16 * STEP;
  int* row_ptr   = (int*)(w2t + W2_ROWS * H_DIM);

  const int setup_items = E + 4096 + W2_ROWS * H_DIM;
  setup_kernel<<<(setup_items + 255) / 256, 256, 0, stream>>>(
      edst, E, row_ptr, N, W1, W2, b_frag, w2t);
  fused_dense_kernel<<<nblk, 256, 0, stream>>>(feat, b_frag, w2t, z0, N);
  spmm_kernel<<<(N + 3) / 4, 256, 0, stream>>>(row_ptr, esrc, evalp, z0, z1, nullptr, N, 0);
  spmm_kernel<<<(N + 3) / 4, 256, 0, stream>>>(row_ptr, esrc, evalp, z1, nullptr, out, N, 1);
}

// Round 7
// 273.670 us; speedup vs baseline: 1.1033x; 1.0061x over previous
//
#include <hip/hip_runtime.h>
#include <cstddef>
#include <cstdint>

#define IN_DIM 256
#define H_DIM  128
#define C_DIM  40
#define BM     128
#define LDA    264   // ushort stride of A-slab rows in LDS (528 B, 2-way-free writes)
#define LDH    136   // ushort stride of per-wave h tile (272 B rows, conflict-free)
#define PAD_C  40    // z row width in bf16 cols: 40 cols = 80 B
#define STEP   512   // ushorts per ks slab of b_frag/w2f: 64 lanes x 8 bf16

typedef short bf16x8 __attribute__((ext_vector_type(8)));
typedef float f32x16 __attribute__((ext_vector_type(16)));
typedef uint  u32x4  __attribute__((ext_vector_type(4)));

__device__ __forceinline__ ushort f2bf(float f) {   // RNE fp32 -> bf16
  uint u = __builtin_bit_cast(uint, f);
  u += 0x7fffu + ((u >> 16) & 1u);
  return (ushort)(u >> 16);
}
__device__ __forceinline__ float bf2f(uint s) {     // low 16 bits -> f32
  uint u = s << 16;
  return __builtin_bit_cast(float, u);
}
// packed fp32x2 -> bf16x2 (HW cvt if available; manual RNE fallback)
__device__ __forceinline__ uint pack2bf(float a, float b) {
#if __has_builtin(__builtin_amdgcn_cvt_pk_bf16_f32)
  typedef __bf16 bf16v2 __attribute__((ext_vector_type(2)));
  bf16v2 r = __builtin_amdgcn_cvt_pk_bf16_f32(a, b);
  return __builtin_bit_cast(uint, r);
#else
  return (uint)f2bf(a) | ((uint)f2bf(b) << 16);
#endif
}

// ---------------------------------------------------------------------------
// Setup (one launch):
//  tid < E:     CSR row_ptr via boundary scan of sorted dst (coalesced O(E)).
//  next 4096:   W1 -> b_frag (MFMA B-fragment order for GEMM1).
//  next 1024:   W2 -> w2f   (MFMA B-fragment order for GEMM2, zero-pad n>=40).
// b_frag[tn][ks][l] (ushort8) = W1[16ks + (l>>5)*8 + j][32tn + (l&31)]
// w2f[kb][tn][l]    (ushort8) = W2[16kb + (l>>5)*8 + j][32tn + (l&31)] (0 pad)
// ---------------------------------------------------------------------------
__global__ void setup_kernel(const int* __restrict__ dst, int E,
                             int* __restrict__ row_ptr, int N,
                             const float* __restrict__ W1,
                             const float* __restrict__ W2,
                             ushort* __restrict__ b_frag,
                             ushort* __restrict__ w2f) {
  int tid = blockIdx.x * blockDim.x + threadIdx.x;
  if (tid < E) {
    int d1 = dst[tid];
    int d0 = (tid == 0) ? -1 : dst[tid - 1];
    for (int v = d0 + 1; v <= d1; ++v) row_ptr[v] = tid;
    if (tid == E - 1)
      for (int v = d1 + 1; v <= N; ++v) row_ptr[v] = E;
    return;
  }
  int u = tid - E;
  if (u < 4096) {                               // W1 -> b_frag fragment order
    int l = u & 63, ks = (u >> 6) & 15, tn = u >> 10;
    int n  = 32 * tn + (l & 31);
    int k0 = ks * 16 + ((l >> 5) << 3);
    ushort r[8];
#pragma unroll
    for (int j = 0; j < 8; ++j) r[j] = f2bf(W1[(k0 + j) * H_DIM + n]);
    *(uint4*)(b_frag + u * 8) = *(uint4*)r;
    return;
  }
  u -= 4096;
  if (u < 1024) {                               // W2 -> w2f fragment order
    int l = u & 63, kt = u >> 6;                // kt = kb*2 + tn
    int tn = kt & 1, kb = kt >> 1;
    int n  = 32 * tn + (l & 31);
    int k0 = kb * 16 + ((l >> 5) << 3);
    ushort r[8];
#pragma unroll
    for (int j = 0; j < 8; ++j)
      r[j] = (n < C_DIM) ? f2bf(W2[(k0 + j) * C_DIM + n]) : (ushort)0;
    *(uint4*)(w2f + u * 8) = *(uint4*)r;
  }
}

// ---------------------------------------------------------------------------
// Fused dense MLP: z0[n][0:40] = relu(feat[n] @ W1) @ W2, bf16, row stride 40.
// Block 256 thr (4 waves), 67584 B LDS -> 2 blocks/CU, 8 waves/CU.
// ZERO BARRIERS: each wave is fully self-contained on its own 32 rows.
//  - stage own 32x256 A-slab into PRIVATE LDS region (64 lanes x 16 B = 1 KB
//    contiguous per instr; ds_write 2-way conflict-free; same-wave RAW needs
//    only lgkmcnt, which the compiler inserts).
//  - GEMM1: A-fragments from own LDS, B ping-pong from L2-resident b_frag.
//  - relu(h) -> own LDS region (aliases own A slab; wave-private, safe).
//  - GEMM2: h-fragments from own LDS, W2-fragments from L2-resident w2f.
// Waves desynchronize freely -> staging (HBM) of some waves overlaps MFMA of
// others; no stage->barrier->compute duty-cycle loss.
// ---------------------------------------------------------------------------
__global__ __launch_bounds__(256, 2) void fused_dense_kernel(
    const float* __restrict__ feat, const ushort* __restrict__ b_frag,
    const ushort* __restrict__ w2f, ushort* __restrict__ z0, int N) {
  __shared__ __align__(16) ushort smem[128 * LDA];   // 4 x 8448 ushort wave slabs

  const int t = threadIdx.x;
  const int w = t >> 6, l = t & 63;
  const int nb = blockIdx.x * BM;
  ushort* slab = smem + w * (32 * LDA);              // this wave's private region

  f32x16 acc[4];
#pragma unroll
  for (int tn = 0; tn < 4; ++tn)
#pragma unroll
    for (int r = 0; r < 16; ++r) acc[tn][r] = 0.f;

  const ushort* bp = b_frag + l * 8;
  bf16x8 Bx[2][4];
#pragma unroll
  for (int tn = 0; tn < 4; ++tn)
    Bx[0][tn] = *(const bf16x8*)(bp + tn * (16 * STEP));

  // ---- stage own A-slab: iter c -> slab row c, lane l -> 16 B slot l
#pragma unroll
  for (int c = 0; c < 32; ++c) {
    int grow = nb + 32 * w + c; if (grow >= N) grow = N - 1;
    float4 v = *(const float4*)(feat + (size_t)grow * IN_DIM + l * 4);
    uint2 pk;
    pk.x = pack2bf(v.x, v.y);
    pk.y = pack2bf(v.z, v.w);
    *(uint2*)(slab + c * LDA + l * 4) = pk;
  }

  // ---- GEMM1: 16 K-steps, A from own LDS, B ping-pong from global (L2)
  const ushort* Abase = slab + (l & 31) * LDA + ((l >> 5) << 3);
#pragma unroll
  for (int ks = 0; ks < 16; ++ks) {
    const int c = ks & 1;
    if (ks < 15) {                              // prefetch next B K-step
#pragma unroll
      for (int tn = 0; tn < 4; ++tn)
        Bx[c ^ 1][tn] = *(const bf16x8*)(bp + tn * (16 * STEP) + (ks + 1) * STEP);
    }
    bf16x8 af = *(const bf16x8*)(Abase + ks * 16);
#pragma unroll
    for (int tn = 0; tn < 4; ++tn)
      acc[tn] = __builtin_amdgcn_mfma_f32_32x32x16_bf16(af, Bx[c][tn], acc[tn], 0, 0, 0);
  }

  // ---- relu(h) -> own LDS region (local node nl = 0..31), aliases A slab
#pragma unroll
  for (int tn = 0; tn < 4; ++tn) {
    int col = tn * 32 + (l & 31);
#pragma unroll
    for (int r = 0; r < 16; ++r) {
      int nl = (r & 3) + 8 * (r >> 2) + 4 * (l >> 5);
      float v = acc[tn][r];
      slab[nl * LDH + col] = f2bf(v > 0.f ? v : 0.f);
    }
  }

  // ---- GEMM2: h-fragments from own LDS, W2-fragments from global w2f (L2)
  f32x16 acc2[2];
#pragma unroll
  for (int tn = 0; tn < 2; ++tn)
#pragma unroll
    for (int r = 0; r < 16; ++r) acc2[tn][r] = 0.f;

  const ushort* Hbase = slab + (l & 31) * LDH + ((l >> 5) << 3);
  const ushort* wp = w2f + l * 8;
#pragma unroll
  for (int kb = 0; kb < 8; ++kb) {
    bf16x8 af = *(const bf16x8*)(Hbase + kb * 16);
#pragma unroll
    for (int tn = 0; tn < 2; ++tn) {
      bf16x8 bfr = *(const bf16x8*)(wp + (kb * 2 + tn) * STEP);
      acc2[tn] = __builtin_amdgcn_mfma_f32_32x32x16_bf16(af, bfr, acc2[tn], 0, 0, 0);
    }
  }

  // store z0 cols 0..39 only (row stride PAD_C = 40)
#pragma unroll
  for (int tn = 0; tn < 2; ++tn) {
    int col = tn * 32 + (l & 31);
    if (col < C_DIM) {
#pragma unroll
      for (int r = 0; r < 16; ++r) {
        int node = nb + 32 * w + (r & 3) + 8 * (r >> 2) + 4 * (l >> 5);
        if (node < N) z0[(size_t)node * PAD_C + col] = f2bf(acc2[tn][r]);
      }
    }
  }
}

// ---------------------------------------------------------------------------
// SPMM (CSR, dst-sorted): one wave per node. lane = 8*h + j (h = edge slot,
// j = col oct). Rows are 40 bf16 cols = 80 B -> only lanes with j < 5
// gather/FMA. Main loop unrolled x2 (16 edges/iter). Butterfly-reduce slots.
// ---------------------------------------------------------------------------
__global__ __launch_bounds__(256) void spmm_kernel(
    const int* __restrict__ row_ptr, const int* __restrict__ esrc,
    const float* __restrict__ eval, const ushort* __restrict__ x,
    ushort* __restrict__ zb, float* __restrict__ zf, int N, int out_f32) {
  int node = (blockIdx.x << 2) + (threadIdx.x >> 6);
  if (node >= N) return;
  const int lane = threadIdx.x & 63;
  const int h = lane >> 3;          // edge slot
  const int j = lane & 7;           // col oct: cols 8j..8j+7 (j<5 active)
  const bool act = (j < 5);

  int e   = row_ptr[node];
  int end = row_ptr[node + 1];

  float acc[8];
#pragma unroll
  for (int c = 0; c < 8; ++c) acc[c] = 0.f;

  // 16 edges per iteration: two independent gather chains
  for (; e + 16 <= end; e += 16) {
    int   s0 = esrc[e + h];
    int   s1 = esrc[e + 8 + h];
    float v0 = eval[e + h];
    float v1 = eval[e + 8 + h];
    if (act) {
      u32x4 a = *(const u32x4*)(x + (size_t)s0 * PAD_C + j * 8);
      u32x4 b = *(const u32x4*)(x + (size_t)s1 * PAD_C + j * 8);
      acc[0] = fmaf(v0, bf2f(a.x & 0xffffu), acc[0]);
      acc[1] = fmaf(v0, bf2f(a.x >> 16),     acc[1]);
      acc[2] = fmaf(v0, bf2f(a.y & 0xffffu), acc[2]);
      acc[3] = fmaf(v0, bf2f(a.y >> 16),     acc[3]);
      acc[4] = fmaf(v0, bf2f(a.z & 0xffffu), acc[4]);
      acc[5] = fmaf(v0, bf2f(a.z >> 16),     acc[5]);
      acc[6] = fmaf(v0, bf2f(a.w & 0xffffu), acc[6]);
      acc[7] = fmaf(v0, bf2f(a.w >> 16),     acc[7]);
      acc[0] = fmaf(v1, bf2f(b.x & 0xffffu), acc[0]);
      acc[1] = fmaf(v1, bf2f(b.x >> 16),     acc[1]);
      acc[2] = fmaf(v1, bf2f(b.y & 0xffffu), acc[2]);
      acc[3] = fmaf(v1, bf2f(b.y >> 16),     acc[3]);
      acc[4] = fmaf(v1, bf2f(b.z & 0xffffu), acc[4]);
      acc[5] = fmaf(v1, bf2f(b.z >> 16),     acc[5]);
      acc[6] = fmaf(v1, bf2f(b.w & 0xffffu), acc[6]);
      acc[7] = fmaf(v1, bf2f(b.w >> 16),     acc[7]);
    }
  }
  for (; e + 8 <= end; e += 8) {
    int   s = esrc[e + h];
    float v = eval[e + h];
    if (act) {
      u32x4 u = *(const u32x4*)(x + (size_t)s * PAD_C + j * 8);
      acc[0] = fmaf(v, bf2f(u.x & 0xffffu), acc[0]);
      acc[1] = fmaf(v, bf2f(u.x >> 16),     acc[1]);
      acc[2] = fmaf(v, bf2f(u.y & 0xffffu), acc[2]);
      acc[3] = fmaf(v, bf2f(u.y >> 16),     acc[3]);
      acc[4] = fmaf(v, bf2f(u.z & 0xffffu), acc[4]);
      acc[5] = fmaf(v, bf2f(u.z >> 16),     acc[5]);
      acc[6] = fmaf(v, bf2f(u.w & 0xffffu), acc[6]);
      acc[7] = fmaf(v, bf2f(u.w >> 16),     acc[7]);
    }
  }
  if (e < end) {                    // tail: clamp slots past the end, weight 0
    int ei = e + h;
    int ec = ei < end ? ei : end - 1;
    int   s  = esrc[ec];
    float v0 = eval[ec];
    float v  = ei < end ? v0 : 0.f;
    if (act) {
      u32x4 u = *(const u32x4*)(x + (size_t)s * PAD_C + j * 8);
      acc[0] = fmaf(v, bf2f(u.x & 0xffffu), acc[0]);
      acc[1] = fmaf(v, bf2f(u.x >> 16),     acc[1]);
      acc[2] = fmaf(v, bf2f(u.y & 0xffffu), acc[2]);
      acc[3] = fmaf(v, bf2f(u.y >> 16),     acc[3]);
      acc[4] = fmaf(v, bf2f(u.z & 0xffffu), acc[4]);
      acc[5] = fmaf(v, bf2f(u.z >> 16),     acc[5]);
      acc[6] = fmaf(v, bf2f(u.w & 0xffffu), acc[6]);
      acc[7] = fmaf(v, bf2f(u.w >> 16),     acc[7]);
    }
  }

  // reduce across the 8 edge slots (lane bits 3..5); partners share j
#pragma unroll
  for (int c = 0; c < 8; ++c) acc[c] += __shfl_xor(acc[c], 8);
#pragma unroll
  for (int c = 0; c < 8; ++c) acc[c] += __shfl_xor(acc[c], 16);
#pragma unroll
  for (int c = 0; c < 8; ++c) acc[c] += __shfl_xor(acc[c], 32);

  if (out_f32) {
    if (lane < 5) {                 // lanes 0..4: j=0..4 -> cols 0..39
      float4 o0 = {acc[0], acc[1], acc[2], acc[3]};
      float4 o1 = {acc[4], acc[5], acc[6], acc[7]};
      float* p = zf + (size_t)node * C_DIM + j * 8;
      *(float4*)(p + 0) = o0;
      *(float4*)(p + 4) = o1;
    }
  } else {
    if (lane < 5) {                 // lanes 0..4: j=0..4 -> cols 0..39
      uint4 p;
      p.x = (uint)f2bf(acc[0]) | ((uint)f2bf(acc[1]) << 16);
      p.y = (uint)f2bf(acc[2]) | ((uint)f2bf(acc[3]) << 16);
      p.z = (uint)f2bf(acc[4]) | ((uint)f2bf(acc[5]) << 16);
      p.w = (uint)f2bf(acc[6]) | ((uint)f2bf(acc[7]) << 16);
      *(uint4*)(zb + (size_t)node * PAD_C + j * 8) = p;
    }
  }
}

// ---------------------------------------------------------------------------
extern "C" void kernel_launch(void* const* d_in, const int* in_sizes, int n_in,
                              void* d_out, int out_size, void* d_ws, size_t ws_size,
                              hipStream_t stream) {
  const float* feat  = (const float*)d_in[0];
  const float* W1    = (const float*)d_in[1];
  const float* W2    = (const float*)d_in[2];
  const int*   esrc  = (const int*)d_in[3];
  const int*   edst  = (const int*)d_in[4];
  const float* evalp = (const float*)d_in[5];
  float* out = (float*)d_out;

  const int N = in_sizes[0] / IN_DIM;   // 100000
  const int E = in_sizes[3];            // 1600000

  const int nblk = (N + BM - 1) / BM;   // GEMM1 blocks

  // ws: z0 bf16 [N][40] | z1 bf16 [N][40] | b_frag (64 KB) | w2f (16 KB) | row_ptr
  char* ws = (char*)d_ws;
  ushort* z0     = (ushort*)ws;
  ushort* z1     = (ushort*)(ws + (size_t)N * PAD_C * 2);
  ushort* b_frag = (ushort*)(ws + (size_t)N * PAD_C * 4);
  ushort* w2f    = b_frag + 4 * 16 * STEP;
  int* row_ptr   = (int*)(w2f + 16 * STEP);

  const int setup_items = E + 4096 + 1024;
  setup_kernel<<<(setup_items + 255) / 256, 256, 0, stream>>>(
      edst, E, row_ptr, N, W1, W2, b_frag, w2f);
  fused_dense_kernel<<<nblk, 256, 0, stream>>>(feat, b_frag, w2f, z0, N);
  spmm_kernel<<<(N + 3) / 4, 256, 0, stream>>>(row_ptr, esrc, evalp, z0, z1, nullptr, N, 0);
  spmm_kernel<<<(N + 3) / 4, 256, 0, stream>>>(row_ptr, esrc, evalp, z1, nullptr, out, N, 1);
}